// Round 5
// baseline (71939.270 us; speedup 1.0000x reference)
//
#include <hip/hip_runtime.h>
#include <float.h>

// TransitionDown: FPS -> kNN(16) -> Linear(64,128)+BN(train stats)+ReLU -> neighborhood max
#define N_PTS 32768
#define M_CL  8192
#define IN_C  64
#define OUT_C 128
#define K_NN  16
constexpr float BN_EPS_C = 1e-5f;

// ---------------- ws layout (bytes) ----------------
// 0        posx [N] f32          (prep -> fps/knn)
// 131072   posy [N]
// 262144   posz [N]
// 393216   psx  [N] sorted       (scatter -> fps)   [psum after fps]
// 524288   psy  [N]
// 655360   psz  [N]              [psumsq after fps]
// 786432   soidx[N] int
// 917504   cellid [N] int        (prep -> scatter)
// 1048576  hist [4096] int       [scale/shift after scatter]
// 1064960  start [4096] int
// 1081344  cur  [4096] int
// 1097728  ids  [M] int          (fps -> knn)
// 1130496  nn   [M*16] int       (knn -> pool)
// 2097152  h [N*128] f32 (16 MiB) -> end 18874368

// ---------------------------------------------------------------------------
__global__ void zero_kernel(int* __restrict__ hist, int* __restrict__ cur) {
    int i = blockIdx.x * 256 + threadIdx.x;
    if (i < 4096) { hist[i] = 0; cur[i] = 0; }
}

__device__ __forceinline__ unsigned sp4(unsigned x) {
    x = (x | (x << 4)) & 0xC3u;
    x = (x | (x << 2)) & 0x249u;
    return x;
}

// 0) SoA split + Morton cell id + histogram
__global__ void prep_kernel(const float* __restrict__ pos,
                            float* __restrict__ px, float* __restrict__ py, float* __restrict__ pz,
                            int* __restrict__ cellid, int* __restrict__ hist) {
    int i = blockIdx.x * 256 + threadIdx.x;
    if (i >= N_PTS) return;
    float x = pos[3 * i + 0], y = pos[3 * i + 1], z = pos[3 * i + 2];
    px[i] = x; py[i] = y; pz[i] = z;
    int cx = (int)floorf((x + 4.0f) * 2.0f); cx = min(15, max(0, cx));
    int cy = (int)floorf((y + 4.0f) * 2.0f); cy = min(15, max(0, cy));
    int cz = (int)floorf((z + 4.0f) * 2.0f); cz = min(15, max(0, cz));
    int c = (int)(sp4((unsigned)cx) | (sp4((unsigned)cy) << 1) | (sp4((unsigned)cz) << 2));
    cellid[i] = c;
    atomicAdd(&hist[c], 1);
}

// exclusive prefix sum over 4096 bins
__global__ __launch_bounds__(1024) void scan_kernel(const int* __restrict__ hist,
                                                    int* __restrict__ start) {
    __shared__ int wtotI[16];
    const int tid = threadIdx.x;
    const int lane = tid & 63, w = tid >> 6;
    int4 hv = *reinterpret_cast<const int4*>(&hist[tid * 4]);
    int a0 = hv.x, a1 = a0 + hv.y, a2 = a1 + hv.z, a3 = a2 + hv.w;
    int tsum = a3;
    int v = tsum;
    #pragma unroll
    for (int off = 1; off < 64; off <<= 1) {
        int o = __shfl_up(v, off);
        if (lane >= off) v += o;
    }
    if (lane == 63) wtotI[w] = v;
    __syncthreads();
    if (tid < 16) {
        int v2 = wtotI[tid];
        #pragma unroll
        for (int off = 1; off < 16; off <<= 1) {
            int o = __shfl_up(v2, off);
            if (tid >= off) v2 += o;
        }
        wtotI[tid] = v2;
    }
    __syncthreads();
    int base = (w > 0 ? wtotI[w - 1] : 0) + (v - tsum);
    int4 sv;
    sv.x = base; sv.y = base + a0; sv.z = base + a1; sv.w = base + a2;
    *reinterpret_cast<int4*>(&start[tid * 4]) = sv;
}

__global__ void scatter_kernel(const float* __restrict__ px, const float* __restrict__ py,
                               const float* __restrict__ pz, const int* __restrict__ cellid,
                               const int* __restrict__ start, int* __restrict__ cur,
                               float* __restrict__ psx, float* __restrict__ psy,
                               float* __restrict__ psz, int* __restrict__ soidx) {
    int i = blockIdx.x * 256 + threadIdx.x;
    if (i >= N_PTS) return;
    int c = cellid[i];
    int p = start[c] + atomicAdd(&cur[c], 1);
    psx[p] = px[i]; psy[p] = py[i]; psz[p] = pz[i];
    soidx[p] = i;
}

// ---------------------------------------------------------------------------
__device__ __forceinline__ unsigned long long shfl_xor_u64(unsigned long long v, int off) {
    unsigned lo = (unsigned)v, hi = (unsigned)(v >> 32);
    lo = __shfl_xor(lo, off);
    hi = __shfl_xor(hi, off);
    return ((unsigned long long)hi << 32) | (unsigned long long)lo;
}

// 1) FPS, fully wave-cooperative, zero register arrays.
//    512 thr / 8 waves. Region = 64 sorted points; wave w owns regions
//    [w*64,(w+1)*64); lane k owns region w*64+k's META ONLY (cen,rad,ckey,
//    cached argmax coords). min_d in LDS [r*64+lane] (2-way bank = free).
//    Key: u64 = (f32bits(min_d)<<32) | (0x7fffffff - origidx) -> u64 max
//    == lex (min_d desc, origidx asc) == np.argmax first-occurrence.
//    Selection carries winner COORDS through the reduction (no L2 on the
//    critical path). Distances bit-identical to jax f32 (unfused, (xx+yy)+zz).
__global__ __launch_bounds__(512) void fps_kernel(
    const float* __restrict__ psx, const float* __restrict__ psy, const float* __restrict__ psz,
    const int* __restrict__ soidx,
    const float* __restrict__ posx, const float* __restrict__ posy, const float* __restrict__ posz,
    const int* __restrict__ batch,
    int* __restrict__ ids, float* __restrict__ out_subpos, float* __restrict__ out_subbatch) {
    #pragma clang fp contract(off)
    __shared__ __align__(16) float mdL[N_PTS];   // 128 KiB
    __shared__ unsigned long long partK[2][8];
    __shared__ float partX[2][8], partY[2][8], partZ[2][8];

    const int tid = threadIdx.x;
    const int lane = tid & 63, w = tid >> 6;

    // per-lane region meta (region w*64 + lane)
    float cenx = 0.0f, ceny = 0.0f, cenz = 0.0f, rad = 0.0f;
    unsigned long long ckey = 0ull;
    float ccx = 0.0f, ccy = 0.0f, ccz = 0.0f;
    // wave-level cached partial
    unsigned long long wvK = 0ull; float wvX = 0.0f, wvY = 0.0f, wvZ = 0.0f;

    const float s0x = posx[0], s0y = posy[0], s0z = posz[0];

    // ---- init: per region k (coop): bbox, md vs point 0, cached max ----
    for (int k = 0; k < 64; ++k) {
        const int r = (w << 6) + k;
        const int gi = (r << 6) + lane;
        float X = psx[gi], Y = psy[gi], Z = psz[gi];
        int   o = soidx[gi];
        float mnx = X, mxx = X, mny = Y, mxy = Y, mnz = Z, mxz = Z;
        float dx = X - s0x;
        float dy = Y - s0y;
        float dz = Z - s0z;
        float xx = dx * dx, yy = dy * dy, zz = dz * dz;
        float d = (xx + yy) + zz;
        mdL[gi] = d;
        unsigned long long kp = ((unsigned long long)__float_as_uint(d) << 32)
                              | (unsigned long long)(0x7fffffffu - (unsigned)o);
        unsigned long long wp = kp;
        #pragma unroll
        for (int off = 32; off; off >>= 1) {
            unsigned long long ok = shfl_xor_u64(wp, off);
            if (ok > wp) wp = ok;
            mnx = fminf(mnx, __shfl_xor(mnx, off)); mxx = fmaxf(mxx, __shfl_xor(mxx, off));
            mny = fminf(mny, __shfl_xor(mny, off)); mxy = fmaxf(mxy, __shfl_xor(mxy, off));
            mnz = fminf(mnz, __shfl_xor(mnz, off)); mxz = fmaxf(mxz, __shfl_xor(mxz, off));
        }
        unsigned long long eqm = __ballot(kp == wp);
        int wl = (int)__ffsll(eqm) - 1;
        float mx_ = __shfl(X, wl), my_ = __shfl(Y, wl), mz_ = __shfl(Z, wl);
        if (lane == k) {
            cenx = 0.5f * (mnx + mxx); ceny = 0.5f * (mny + mxy); cenz = 0.5f * (mnz + mxz);
            float hx = mxx - cenx, hy = mxy - ceny, hz = mxz - cenz;
            rad = sqrtf((hx * hx + hy * hy) + hz * hz) * 1.0005f + 1e-6f;
            ckey = wp; ccx = mx_; ccy = my_; ccz = mz_;
        }
    }
    // wave partial for step 1
    {
        unsigned long long wk = ckey; float wx = ccx, wy = ccy, wz = ccz;
        #pragma unroll
        for (int off = 32; off; off >>= 1) {
            unsigned long long ok = shfl_xor_u64(wk, off);
            float ox = __shfl_xor(wx, off), oy = __shfl_xor(wy, off), oz = __shfl_xor(wz, off);
            if (ok > wk) { wk = ok; wx = ox; wy = oy; wz = oz; }
        }
        wvK = wk; wvX = wx; wvY = wy; wvZ = wz;
        if (lane == 0) { partK[1][w] = wk; partX[1][w] = wx; partY[1][w] = wy; partZ[1][w] = wz; }
    }
    if (tid == 0) {
        ids[0] = 0;
        out_subpos[0] = s0x; out_subpos[1] = s0y; out_subpos[2] = s0z;
        out_subbatch[0] = (float)batch[0];
    }
    __syncthreads();

    // ---- main loop: one barrier per step ----
    for (int t = 1; t < M_CL; ++t) {
        const int tb = t & 1;
        // A: redundant final reduce over 8 wave partials (LDS broadcast reads)
        unsigned long long bk = partK[tb][0];
        float sx = partX[tb][0], sy = partY[tb][0], sz = partZ[tb][0];
        #pragma unroll
        for (int u = 1; u < 8; ++u) {
            unsigned long long ok = partK[tb][u];
            if (ok > bk) { bk = ok; sx = partX[tb][u]; sy = partY[tb][u]; sz = partZ[tb][u]; }
        }
        if (tid == 0) {
            int oi = (int)(0x7fffffffu - (unsigned)(bk & 0xffffffffu));
            ids[t] = oi;
            out_subpos[3 * t + 0] = sx;
            out_subpos[3 * t + 1] = sy;
            out_subpos[3 * t + 2] = sz;
            out_subbatch[t] = (float)batch[oi];
        }
        // B: prune test, one region per lane
        float ex = sx - cenx, ey = sy - ceny, ez = sz - cenz;
        float dc2 = (ex * ex + ey * ey) + ez * ez;
        float lb = sqrtf(dc2) * 0.9995f - rad;
        float cmaxf = __uint_as_float((unsigned)(ckey >> 32));
        bool aff = !(lb > 0.0f && lb * lb * 0.999f >= cmaxf);
        unsigned long long m = __ballot(aff);

        // C: coop update of affected regions, 1-ahead coord prefetch
        if (m) {
            unsigned long long mm = m;
            int kA = (int)__ffsll(mm) - 1; mm &= mm - 1;
            int giA = (((w << 6) + kA) << 6) + lane;
            float xA = psx[giA], yA = psy[giA], zA = psz[giA];
            int oA = soidx[giA];
            while (kA >= 0) {
                int kB = -1; float xB = 0, yB = 0, zB = 0; int oB = 0;
                if (mm) {
                    kB = (int)__ffsll(mm) - 1; mm &= mm - 1;
                    int giB = (((w << 6) + kB) << 6) + lane;
                    xB = psx[giB]; yB = psy[giB]; zB = psz[giB]; oB = soidx[giB];
                }
                // process region kA
                int gi = (((w << 6) + kA) << 6) + lane;
                float dx = xA - sx;
                float dy = yA - sy;
                float dz = zA - sz;
                float xx = dx * dx, yy = dy * dy, zz = dz * dz;
                float d = (xx + yy) + zz;
                float nm = fminf(mdL[gi], d);
                mdL[gi] = nm;
                unsigned long long kp = ((unsigned long long)__float_as_uint(nm) << 32)
                                      | (unsigned long long)(0x7fffffffu - (unsigned)oA);
                unsigned long long wp = kp;
                #pragma unroll
                for (int off = 32; off; off >>= 1) {
                    unsigned long long ok = shfl_xor_u64(wp, off);
                    if (ok > wp) wp = ok;
                }
                unsigned long long eqm = __ballot(kp == wp);
                int wl = (int)__ffsll(eqm) - 1;
                float mx_ = __shfl(xA, wl), my_ = __shfl(yA, wl), mz_ = __shfl(zA, wl);
                if (lane == kA) { ckey = wp; ccx = mx_; ccy = my_; ccz = mz_; }
                kA = kB; xA = xB; yA = yB; zA = zB; oA = oB;
            }
            // D: wave cache butterfly (only when this wave changed)
            unsigned long long wk = ckey; float wx = ccx, wy = ccy, wz = ccz;
            #pragma unroll
            for (int off = 32; off; off >>= 1) {
                unsigned long long ok = shfl_xor_u64(wk, off);
                float ox = __shfl_xor(wx, off), oy = __shfl_xor(wy, off), oz = __shfl_xor(wz, off);
                if (ok > wk) { wk = ok; wx = ox; wy = oy; wz = oz; }
            }
            wvK = wk; wvX = wx; wvY = wy; wvZ = wz;
        }
        if (lane == 0) {
            const int nb = (t + 1) & 1;
            partK[nb][w] = wvK; partX[nb][w] = wvX; partY[nb][w] = wvY; partZ[nb][w] = wvZ;
        }
        __syncthreads();
    }
}

// ---------------------------------------------------------------------------
// 2) GEMM h = x@W + b (f32 vector ALU) + fused per-block column sum / sumsq.
__global__ __launch_bounds__(256) void gemm_stats_kernel(
    const float* __restrict__ x, const float* __restrict__ W, const float* __restrict__ bias,
    float* __restrict__ h, float* __restrict__ psum, float* __restrict__ psumsq) {
    __shared__ __align__(16) float Wl[64 * 128];
    __shared__ float xl[64 * 64];
    __shared__ float st[8 * 128 * 2];

    const int t = threadIdx.x;
    const int r0 = blockIdx.x * 64;
    #pragma unroll
    for (int u = 0; u < 32; ++u) Wl[u * 256 + t] = W[u * 256 + t];
    #pragma unroll
    for (int u = 0; u < 16; ++u) { int f = u * 256 + t; xl[f] = x[r0 * 64 + f]; }
    __syncthreads();

    const int cg = t & 31;
    const int rg = t >> 5;
    float acc[8][4];
    #pragma unroll
    for (int j = 0; j < 8; ++j)
        #pragma unroll
        for (int cc = 0; cc < 4; ++cc) acc[j][cc] = 0.0f;

    #pragma unroll 4
    for (int k = 0; k < 64; ++k) {
        float4 w4 = *reinterpret_cast<const float4*>(&Wl[k * 128 + cg * 4]);
        #pragma unroll
        for (int j = 0; j < 8; ++j) {
            float xv = xl[(rg * 8 + j) * 64 + k];
            acc[j][0] = fmaf(xv, w4.x, acc[j][0]);
            acc[j][1] = fmaf(xv, w4.y, acc[j][1]);
            acc[j][2] = fmaf(xv, w4.z, acc[j][2]);
            acc[j][3] = fmaf(xv, w4.w, acc[j][3]);
        }
    }
    float4 b4 = *reinterpret_cast<const float4*>(&bias[cg * 4]);
    float s1[4] = {0, 0, 0, 0}, s2[4] = {0, 0, 0, 0};
    #pragma unroll
    for (int j = 0; j < 8; ++j) {
        float4 hv;
        hv.x = acc[j][0] + b4.x;
        hv.y = acc[j][1] + b4.y;
        hv.z = acc[j][2] + b4.z;
        hv.w = acc[j][3] + b4.w;
        *reinterpret_cast<float4*>(&h[(r0 + rg * 8 + j) * 128 + cg * 4]) = hv;
        s1[0] += hv.x; s2[0] += hv.x * hv.x;
        s1[1] += hv.y; s2[1] += hv.y * hv.y;
        s1[2] += hv.z; s2[2] += hv.z * hv.z;
        s1[3] += hv.w; s2[3] += hv.w * hv.w;
    }
    #pragma unroll
    for (int cc = 0; cc < 4; ++cc) {
        st[(rg * 128 + cg * 4 + cc) * 2 + 0] = s1[cc];
        st[(rg * 128 + cg * 4 + cc) * 2 + 1] = s2[cc];
    }
    __syncthreads();
    if (t < 128) {
        float a = 0.0f, q = 0.0f;
        #pragma unroll
        for (int g = 0; g < 8; ++g) {
            a += st[(g * 128 + t) * 2 + 0];
            q += st[(g * 128 + t) * 2 + 1];
        }
        psum[blockIdx.x * 128 + t] = a;
        psumsq[blockIdx.x * 128 + t] = q;
    }
}

// ---------------------------------------------------------------------------
__global__ void bn_finalize_kernel(const float* __restrict__ psum, const float* __restrict__ psumsq,
                                   const float* __restrict__ gamma, const float* __restrict__ beta,
                                   float* __restrict__ scale, float* __restrict__ shift) {
    int c = threadIdx.x;
    float s = 0.0f, q = 0.0f;
    #pragma unroll 8
    for (int p = 0; p < 512; ++p) {
        s += psum[p * 128 + c];
        q += psumsq[p * 128 + c];
    }
    float mean = s * (1.0f / N_PTS);
    float var = q * (1.0f / N_PTS) - mean * mean;
    float sc = gamma[c] * rsqrtf(var + BN_EPS_C);
    scale[c] = sc;
    shift[c] = beta[c] - mean * sc;
}

// ---------------------------------------------------------------------------
// 4) kNN: one wave per query; per-lane top-16 lex (d, idx); shuffle merge.
__global__ __launch_bounds__(256) void knn_kernel(
    const float* __restrict__ posx, const float* __restrict__ posy, const float* __restrict__ posz,
    const int* __restrict__ ids, int* __restrict__ nn) {
    const int lane = threadIdx.x & 63;
    const int q = blockIdx.x * 4 + (threadIdx.x >> 6);
    const int qi = ids[q];
    const float qx = posx[qi], qy = posy[qi], qz = posz[qi];

    float dv[16]; int di[16];
    #pragma unroll
    for (int j = 0; j < 16; ++j) { dv[j] = FLT_MAX; di[j] = 0x7fffffff; }
    float wm = FLT_MAX; int wmi = 0x7fffffff; int wslot = 0;

    for (int s = 0; s < N_PTS / 64; ++s) {
        int i = s * 64 + lane;
        float dx = posx[i] - qx, dy = posy[i] - qy, dz = posz[i] - qz;
        float d = fmaf(dx, dx, fmaf(dy, dy, dz * dz));
        if (d < wm || (d == wm && i < wmi)) {
            #pragma unroll
            for (int j = 0; j < 16; ++j)
                if (j == wslot) { dv[j] = d; di[j] = i; }
            wm = -1.0f; wmi = -1;
            #pragma unroll
            for (int j = 0; j < 16; ++j) {
                bool g = (dv[j] > wm) || (dv[j] == wm && di[j] > wmi);
                if (g) { wm = dv[j]; wmi = di[j]; wslot = j; }
            }
        }
    }
    for (int rr = 0; rr < 16; ++rr) {
        float bv = FLT_MAX; int bidx = 0x7fffffff;
        #pragma unroll
        for (int j = 0; j < 16; ++j) {
            bool g = (dv[j] < bv) || (dv[j] == bv && di[j] < bidx);
            if (g) { bv = dv[j]; bidx = di[j]; }
        }
        #pragma unroll
        for (int off = 32; off; off >>= 1) {
            float ov = __shfl_xor(bv, off);
            int oi = __shfl_xor(bidx, off);
            if (ov < bv || (ov == bv && oi < bidx)) { bv = ov; bidx = oi; }
        }
        if (lane == 0) nn[q * 16 + rr] = bidx;
        #pragma unroll
        for (int j = 0; j < 16; ++j)
            if (di[j] == bidx) { dv[j] = FLT_MAX; di[j] = 0x7fffffff; }
    }
}

// ---------------------------------------------------------------------------
__global__ __launch_bounds__(256) void pool_kernel(
    const float* __restrict__ h, const int* __restrict__ nn,
    const float* __restrict__ scale, const float* __restrict__ shift,
    float* __restrict__ out) {
    const int t = threadIdx.x;
    const int c = t & 127;
    const int m = blockIdx.x * 2 + (t >> 7);
    const float sc = scale[c], sh = shift[c];
    float mx = -FLT_MAX;
    #pragma unroll
    for (int k = 0; k < 16; ++k) {
        int n = nn[m * 16 + k];
        float hv = h[n * 128 + c];
        mx = fmaxf(mx, fmaf(hv, sc, sh));
    }
    out[m * 128 + c] = fmaxf(mx, 0.0f);
}

// ---------------------------------------------------------------------------
extern "C" void kernel_launch(void* const* d_in, const int* in_sizes, int n_in,
                              void* d_out, int out_size, void* d_ws, size_t ws_size,
                              hipStream_t stream) {
    const float* x     = (const float*)d_in[0];
    const float* pos   = (const float*)d_in[1];
    const int*   batch = (const int*)d_in[2];
    const float* W     = (const float*)d_in[3];
    const float* b     = (const float*)d_in[4];
    const float* gamma = (const float*)d_in[5];
    const float* beta  = (const float*)d_in[6];
    (void)in_sizes; (void)n_in; (void)out_size; (void)ws_size;

    float* out       = (float*)d_out;
    float* sub_pos   = out + (size_t)M_CL * OUT_C;
    float* sub_batch = sub_pos + (size_t)M_CL * 3;

    char* w8 = (char*)d_ws;
    float* posx   = (float*)(w8 + 0);
    float* posy   = (float*)(w8 + 131072);
    float* posz   = (float*)(w8 + 262144);
    float* psx    = (float*)(w8 + 393216);
    float* psy    = (float*)(w8 + 524288);
    float* psz    = (float*)(w8 + 655360);
    int*   soidx  = (int*)  (w8 + 786432);
    int*   cellid = (int*)  (w8 + 917504);
    int*   hist   = (int*)  (w8 + 1048576);
    int*   startb = (int*)  (w8 + 1064960);
    int*   cur    = (int*)  (w8 + 1081344);
    int*   ids    = (int*)  (w8 + 1097728);
    int*   nn     = (int*)  (w8 + 1130496);
    // dead-region reuse (stream-ordered):
    float* psum   = (float*)(w8 + 393216);   // over psx/psy (dead after fps)
    float* psumsq = (float*)(w8 + 655360);   // over psz/soidx (dead after fps)
    float* scale  = (float*)(w8 + 1048576);  // over hist (dead after scatter)
    float* shift  = (float*)(w8 + 1049088);
    float* h      = (float*)(w8 + 2097152);

    zero_kernel<<<32, 256, 0, stream>>>(hist, cur);
    prep_kernel<<<128, 256, 0, stream>>>(pos, posx, posy, posz, cellid, hist);
    scan_kernel<<<1, 1024, 0, stream>>>(hist, startb);
    scatter_kernel<<<128, 256, 0, stream>>>(posx, posy, posz, cellid, startb, cur,
                                            psx, psy, psz, soidx);
    fps_kernel<<<1, 512, 0, stream>>>(psx, psy, psz, soidx,
                                      posx, posy, posz, batch,
                                      ids, sub_pos, sub_batch);
    gemm_stats_kernel<<<512, 256, 0, stream>>>(x, W, b, h, psum, psumsq);
    bn_finalize_kernel<<<1, 128, 0, stream>>>(psum, psumsq, gamma, beta, scale, shift);
    knn_kernel<<<2048, 256, 0, stream>>>(posx, posy, posz, ids, nn);
    pool_kernel<<<4096, 256, 0, stream>>>(h, nn, scale, shift, out);
}

// Round 6
// 44167.679 us; speedup vs baseline: 1.6288x; 1.6288x over previous
//
#include <hip/hip_runtime.h>
#include <float.h>

// TransitionDown: FPS -> kNN(16) -> Linear(64,128)+BN(train stats)+ReLU -> neighborhood max
#define N_PTS 32768
#define M_CL  8192
#define IN_C  64
#define OUT_C 128
#define K_NN  16
constexpr float BN_EPS_C = 1e-5f;

// ---------------- ws layout (bytes) ----------------
// 0        posx [N] f32          (prep -> fps/knn)
// 131072   posy [N]
// 262144   posz [N]
// 393216   psx  [N] sorted       (scatter -> fps)   [psum after fps]
// 524288   psy  [N]
// 655360   psz  [N]              [psumsq after fps]
// 786432   soidx[N] int
// 917504   cellid [N] int        (prep -> scatter)
// 1048576  hist [4096] int       [scale/shift after scatter]
// 1064960  start [4096] int
// 1081344  cur  [4096] int
// 1097728  ids  [M] int          (fps -> knn/sub_batch)
// 1130496  nn   [M*16] int       (knn -> pool)      ends 1654784
// 1654784  probe scratch [1024] int
// 2097152  h [N*128] f32 (16 MiB) -> end 18874368

// ---------------------------------------------------------------------------
__global__ void zero_kernel(int* __restrict__ hist, int* __restrict__ cur) {
    int i = blockIdx.x * 256 + threadIdx.x;
    if (i < 4096) { hist[i] = 0; cur[i] = 0; }
}

__device__ __forceinline__ unsigned sp4(unsigned x) {
    x = (x | (x << 4)) & 0xC3u;
    x = (x | (x << 2)) & 0x249u;
    return x;
}

// 0) SoA split + Morton cell id + histogram
__global__ void prep_kernel(const float* __restrict__ pos,
                            float* __restrict__ px, float* __restrict__ py, float* __restrict__ pz,
                            int* __restrict__ cellid, int* __restrict__ hist) {
    int i = blockIdx.x * 256 + threadIdx.x;
    if (i >= N_PTS) return;
    float x = pos[3 * i + 0], y = pos[3 * i + 1], z = pos[3 * i + 2];
    px[i] = x; py[i] = y; pz[i] = z;
    int cx = (int)floorf((x + 4.0f) * 2.0f); cx = min(15, max(0, cx));
    int cy = (int)floorf((y + 4.0f) * 2.0f); cy = min(15, max(0, cy));
    int cz = (int)floorf((z + 4.0f) * 2.0f); cz = min(15, max(0, cz));
    int c = (int)(sp4((unsigned)cx) | (sp4((unsigned)cy) << 1) | (sp4((unsigned)cz) << 2));
    cellid[i] = c;
    atomicAdd(&hist[c], 1);
}

// exclusive prefix sum over 4096 bins
__global__ __launch_bounds__(1024) void scan_kernel(const int* __restrict__ hist,
                                                    int* __restrict__ start) {
    __shared__ int wtotI[16];
    const int tid = threadIdx.x;
    const int lane = tid & 63, w = tid >> 6;
    int4 hv = *reinterpret_cast<const int4*>(&hist[tid * 4]);
    int a0 = hv.x, a1 = a0 + hv.y, a2 = a1 + hv.z, a3 = a2 + hv.w;
    int tsum = a3;
    int v = tsum;
    #pragma unroll
    for (int off = 1; off < 64; off <<= 1) {
        int o = __shfl_up(v, off);
        if (lane >= off) v += o;
    }
    if (lane == 63) wtotI[w] = v;
    __syncthreads();
    if (tid < 16) {
        int v2 = wtotI[tid];
        #pragma unroll
        for (int off = 1; off < 16; off <<= 1) {
            int o = __shfl_up(v2, off);
            if (tid >= off) v2 += o;
        }
        wtotI[tid] = v2;
    }
    __syncthreads();
    int base = (w > 0 ? wtotI[w - 1] : 0) + (v - tsum);
    int4 sv;
    sv.x = base; sv.y = base + a0; sv.z = base + a1; sv.w = base + a2;
    *reinterpret_cast<int4*>(&start[tid * 4]) = sv;
}

__global__ void scatter_kernel(const float* __restrict__ px, const float* __restrict__ py,
                               const float* __restrict__ pz, const int* __restrict__ cellid,
                               const int* __restrict__ start, int* __restrict__ cur,
                               float* __restrict__ psx, float* __restrict__ psy,
                               float* __restrict__ psz, int* __restrict__ soidx) {
    int i = blockIdx.x * 256 + threadIdx.x;
    if (i >= N_PTS) return;
    int c = cellid[i];
    int p = start[c] + atomicAdd(&cur[c], 1);
    psx[p] = px[i]; psy[p] = py[i]; psz[p] = pz[i];
    soidx[p] = i;
}

// ---------------------------------------------------------------------------
__device__ __forceinline__ unsigned long long shfl_xor_u64(unsigned long long v, int off) {
    unsigned lo = (unsigned)v, hi = (unsigned)(v >> 32);
    lo = __shfl_xor(lo, off);
    hi = __shfl_xor(hi, off);
    return ((unsigned long long)hi << 32) | (unsigned long long)lo;
}
__device__ __forceinline__ unsigned long long shfl_u64(unsigned long long v, int src) {
    unsigned lo = (unsigned)v, hi = (unsigned)(v >> 32);
    lo = __shfl(lo, src);
    hi = __shfl(hi, src);
    return ((unsigned long long)hi << 32) | (unsigned long long)lo;
}

// 1) FPS, wave-cooperative, lazy max maintenance.
//    512 thr / 8 waves; region = 64 sorted points; lane k owns region w*64+k's
//    meta (cen,rad,ckey,argmax coords). min_d in LDS. Key u64 =
//    (f32bits(min_d)<<32)|(0x7fffffff-origidx): u64 max == (min_d desc, idx asc).
//    Region butterfly runs ONLY when the cached max could change:
//    (argmax's md decreased) or (some md decreased to tie cmax).
//    Distances bit-identical to jax f32 (unfused, (xx+yy)+zz).
__global__ __launch_bounds__(512) void fps_kernel(
    const float* __restrict__ psx, const float* __restrict__ psy, const float* __restrict__ psz,
    const int* __restrict__ soidx,
    const float* __restrict__ posx, const float* __restrict__ posy, const float* __restrict__ posz,
    int* __restrict__ ids, float* __restrict__ out_subpos) {
    #pragma clang fp contract(off)
    __shared__ __align__(16) float mdL[N_PTS];   // 128 KiB
    __shared__ unsigned long long partK[2][8];
    __shared__ float partX[2][8], partY[2][8], partZ[2][8];

    const int tid = threadIdx.x;
    const int lane = tid & 63, w = tid >> 6;

    float cenx = 0.0f, ceny = 0.0f, cenz = 0.0f, rad = 0.0f;
    unsigned long long ckey = 0ull;
    float ccx = 0.0f, ccy = 0.0f, ccz = 0.0f;
    unsigned long long wvK = 0ull; float wvX = 0.0f, wvY = 0.0f, wvZ = 0.0f;

    const float s0x = posx[0], s0y = posy[0], s0z = posz[0];

    // ---- init ----
    for (int k = 0; k < 64; ++k) {
        const int r = (w << 6) + k;
        const int gi = (r << 6) + lane;
        float X = psx[gi], Y = psy[gi], Z = psz[gi];
        int   o = soidx[gi];
        float mnx = X, mxx = X, mny = Y, mxy = Y, mnz = Z, mxz = Z;
        float dx = X - s0x;
        float dy = Y - s0y;
        float dz = Z - s0z;
        float xx = dx * dx, yy = dy * dy, zz = dz * dz;
        float d = (xx + yy) + zz;
        mdL[gi] = d;
        unsigned long long kp = ((unsigned long long)__float_as_uint(d) << 32)
                              | (unsigned long long)(0x7fffffffu - (unsigned)o);
        unsigned long long wp = kp;
        #pragma unroll
        for (int off = 32; off; off >>= 1) {
            unsigned long long ok = shfl_xor_u64(wp, off);
            if (ok > wp) wp = ok;
            mnx = fminf(mnx, __shfl_xor(mnx, off)); mxx = fmaxf(mxx, __shfl_xor(mxx, off));
            mny = fminf(mny, __shfl_xor(mny, off)); mxy = fmaxf(mxy, __shfl_xor(mxy, off));
            mnz = fminf(mnz, __shfl_xor(mnz, off)); mxz = fmaxf(mxz, __shfl_xor(mxz, off));
        }
        unsigned long long eqm = __ballot(kp == wp);
        int wl = (int)__ffsll(eqm) - 1;
        float mx_ = __shfl(X, wl), my_ = __shfl(Y, wl), mz_ = __shfl(Z, wl);
        if (lane == k) {
            cenx = 0.5f * (mnx + mxx); ceny = 0.5f * (mny + mxy); cenz = 0.5f * (mnz + mxz);
            float hx = mxx - cenx, hy = mxy - ceny, hz = mxz - cenz;
            rad = sqrtf((hx * hx + hy * hy) + hz * hz) * 1.0005f + 1e-6f;
            ckey = wp; ccx = mx_; ccy = my_; ccz = mz_;
        }
    }
    {
        unsigned long long wk = ckey; float wx = ccx, wy = ccy, wz = ccz;
        #pragma unroll
        for (int off = 32; off; off >>= 1) {
            unsigned long long ok = shfl_xor_u64(wk, off);
            float ox = __shfl_xor(wx, off), oy = __shfl_xor(wy, off), oz = __shfl_xor(wz, off);
            if (ok > wk) { wk = ok; wx = ox; wy = oy; wz = oz; }
        }
        wvK = wk; wvX = wx; wvY = wy; wvZ = wz;
        if (lane == 0) { partK[1][w] = wk; partX[1][w] = wx; partY[1][w] = wy; partZ[1][w] = wz; }
    }
    if (tid == 0) {
        ids[0] = 0;
        out_subpos[0] = s0x; out_subpos[1] = s0y; out_subpos[2] = s0z;
    }
    __syncthreads();

    // ---- main loop: one barrier per step ----
    for (int t = 1; t < M_CL; ++t) {
        const int tb = t & 1;
        // A: redundant final reduce over 8 wave partials
        unsigned long long bk = partK[tb][0];
        float sx = partX[tb][0], sy = partY[tb][0], sz = partZ[tb][0];
        #pragma unroll
        for (int u = 1; u < 8; ++u) {
            unsigned long long ok = partK[tb][u];
            if (ok > bk) { bk = ok; sx = partX[tb][u]; sy = partY[tb][u]; sz = partZ[tb][u]; }
        }
        if (tid == 0) {
            ids[t] = (int)(0x7fffffffu - (unsigned)(bk & 0xffffffffu));
            out_subpos[3 * t + 0] = sx;
            out_subpos[3 * t + 1] = sy;
            out_subpos[3 * t + 2] = sz;
        }
        // B: prune test, one region per lane
        float ex = sx - cenx, ey = sy - ceny, ez = sz - cenz;
        float dc2 = (ex * ex + ey * ey) + ez * ez;
        float lb = sqrtf(dc2) * 0.9995f - rad;
        float cmaxf = __uint_as_float((unsigned)(ckey >> 32));
        bool aff = !(lb > 0.0f && lb * lb * 0.999f >= cmaxf);
        unsigned long long m = __ballot(aff);

        // C: update affected regions; butterfly only when cached max may change
        bool wchg = false;
        if (m) {
            unsigned long long mm = m;
            int kA = (int)__ffsll(mm) - 1; mm &= mm - 1;
            int giA = (((w << 6) + kA) << 6) + lane;
            float xA = psx[giA], yA = psy[giA], zA = psz[giA];
            int oA = soidx[giA];
            while (kA >= 0) {
                int kB = -1; float xB = 0, yB = 0, zB = 0; int oB = 0;
                if (mm) {
                    kB = (int)__ffsll(mm) - 1; mm &= mm - 1;
                    int giB = (((w << 6) + kB) << 6) + lane;
                    xB = psx[giB]; yB = psy[giB]; zB = psz[giB]; oB = soidx[giB];
                }
                int gi = (((w << 6) + kA) << 6) + lane;
                float dx = xA - sx;
                float dy = yA - sy;
                float dz = zA - sz;
                float xx = dx * dx, yy = dy * dy, zz = dz * dz;
                float d = (xx + yy) + zz;
                float old = mdL[gi];
                float nm = fminf(old, d);
                bool chg = nm < old;
                if (chg) mdL[gi] = nm;
                if (__ballot(chg)) {
                    // did the region's cached max possibly change?
                    unsigned long long rk = shfl_u64(ckey, kA);
                    float cmaxR = __uint_as_float((unsigned)(rk >> 32));
                    unsigned idxR = 0x7fffffffu - (unsigned)(rk & 0xffffffffu);
                    bool danger = chg && (((unsigned)oA == idxR) || (nm == cmaxR));
                    if (__ballot(danger)) {
                        unsigned long long kp = ((unsigned long long)__float_as_uint(nm) << 32)
                                              | (unsigned long long)(0x7fffffffu - (unsigned)oA);
                        unsigned long long wp = kp;
                        #pragma unroll
                        for (int off = 32; off; off >>= 1) {
                            unsigned long long ok = shfl_xor_u64(wp, off);
                            if (ok > wp) wp = ok;
                        }
                        unsigned long long eqm = __ballot(kp == wp);
                        int wl = (int)__ffsll(eqm) - 1;
                        float mx_ = __shfl(xA, wl), my_ = __shfl(yA, wl), mz_ = __shfl(zA, wl);
                        if (lane == kA) { ckey = wp; ccx = mx_; ccy = my_; ccz = mz_; }
                        wchg = true;
                    }
                }
                kA = kB; xA = xB; yA = yB; zA = zB; oA = oB;
            }
            // D: wave cache butterfly only if some region's key changed
            if (wchg) {
                unsigned long long wk = ckey; float wx = ccx, wy = ccy, wz = ccz;
                #pragma unroll
                for (int off = 32; off; off >>= 1) {
                    unsigned long long ok = shfl_xor_u64(wk, off);
                    float ox = __shfl_xor(wx, off), oy = __shfl_xor(wy, off), oz = __shfl_xor(wz, off);
                    if (ok > wk) { wk = ok; wx = ox; wy = oy; wz = oz; }
                }
                wvK = wk; wvX = wx; wvY = wy; wvZ = wz;
            }
        }
        if (lane == 0) {
            const int nb = (t + 1) & 1;
            partK[nb][w] = wvK; partX[nb][w] = wvX; partY[nb][w] = wvY; partZ[nb][w] = wvZ;
        }
        __syncthreads();
    }
}

// ---------------------------------------------------------------------------
// Ablation probe: selection skeleton only (A + D-butterfly + partial write +
// barrier), 1024 steps (1/8 of M_CL). Writes to private scratch; output unused.
// Prices the per-step skeleton floor for next round's profile. Deterministic.
__global__ __launch_bounds__(512) void fps_probe(int* __restrict__ dump) {
    __shared__ unsigned long long partK[2][8];
    __shared__ float partX[2][8], partY[2][8], partZ[2][8];
    const int tid = threadIdx.x;
    const int lane = tid & 63, w = tid >> 6;
    unsigned long long ckey = ((unsigned long long)(tid * 2654435761u) << 32) | (unsigned)tid;
    float ccx = (float)lane, ccy = (float)w, ccz = 1.0f;
    if (tid < 8) { partK[0][tid] = 0; partX[0][tid] = 0; partY[0][tid] = 0; partZ[0][tid] = 0;
                   partK[1][tid] = (unsigned long long)tid; partX[1][tid] = 0; partY[1][tid] = 0; partZ[1][tid] = 0; }
    __syncthreads();
    for (int t = 1; t < 1024; ++t) {
        const int tb = t & 1;
        unsigned long long bk = partK[tb][0];
        float sx = partX[tb][0], sy = partY[tb][0], sz = partZ[tb][0];
        #pragma unroll
        for (int u = 1; u < 8; ++u) {
            unsigned long long ok = partK[tb][u];
            if (ok > bk) { bk = ok; sx = partX[tb][u]; sy = partY[tb][u]; sz = partZ[tb][u]; }
        }
        if (tid == 0) dump[t] = (int)(bk & 0xffffffffu) ^ __float_as_int(sx + sy + sz);
        ckey ^= bk;  // keep live, data-dependent
        unsigned long long wk = ckey; float wx = ccx, wy = ccy, wz = ccz;
        #pragma unroll
        for (int off = 32; off; off >>= 1) {
            unsigned long long ok = shfl_xor_u64(wk, off);
            float ox = __shfl_xor(wx, off), oy = __shfl_xor(wy, off), oz = __shfl_xor(wz, off);
            if (ok > wk) { wk = ok; wx = ox; wy = oy; wz = oz; }
        }
        if (lane == 0) {
            const int nb = (t + 1) & 1;
            partK[nb][w] = wk; partX[nb][w] = wx; partY[nb][w] = wy; partZ[nb][w] = wz;
        }
        __syncthreads();
    }
}

// ---------------------------------------------------------------------------
// sub_batch gather (moved off fps critical path)
__global__ void sub_batch_kernel(const int* __restrict__ ids, const int* __restrict__ batch,
                                 float* __restrict__ sub_batch) {
    int i = blockIdx.x * 256 + threadIdx.x;
    if (i < M_CL) sub_batch[i] = (float)batch[ids[i]];
}

// ---------------------------------------------------------------------------
// 2) GEMM h = x@W + b (f32 vector ALU) + fused per-block column sum / sumsq.
__global__ __launch_bounds__(256) void gemm_stats_kernel(
    const float* __restrict__ x, const float* __restrict__ W, const float* __restrict__ bias,
    float* __restrict__ h, float* __restrict__ psum, float* __restrict__ psumsq) {
    __shared__ __align__(16) float Wl[64 * 128];
    __shared__ float xl[64 * 64];
    __shared__ float st[8 * 128 * 2];

    const int t = threadIdx.x;
    const int r0 = blockIdx.x * 64;
    #pragma unroll
    for (int u = 0; u < 32; ++u) Wl[u * 256 + t] = W[u * 256 + t];
    #pragma unroll
    for (int u = 0; u < 16; ++u) { int f = u * 256 + t; xl[f] = x[r0 * 64 + f]; }
    __syncthreads();

    const int cg = t & 31;
    const int rg = t >> 5;
    float acc[8][4];
    #pragma unroll
    for (int j = 0; j < 8; ++j)
        #pragma unroll
        for (int cc = 0; cc < 4; ++cc) acc[j][cc] = 0.0f;

    #pragma unroll 4
    for (int k = 0; k < 64; ++k) {
        float4 w4 = *reinterpret_cast<const float4*>(&Wl[k * 128 + cg * 4]);
        #pragma unroll
        for (int j = 0; j < 8; ++j) {
            float xv = xl[(rg * 8 + j) * 64 + k];
            acc[j][0] = fmaf(xv, w4.x, acc[j][0]);
            acc[j][1] = fmaf(xv, w4.y, acc[j][1]);
            acc[j][2] = fmaf(xv, w4.z, acc[j][2]);
            acc[j][3] = fmaf(xv, w4.w, acc[j][3]);
        }
    }
    float4 b4 = *reinterpret_cast<const float4*>(&bias[cg * 4]);
    float s1[4] = {0, 0, 0, 0}, s2[4] = {0, 0, 0, 0};
    #pragma unroll
    for (int j = 0; j < 8; ++j) {
        float4 hv;
        hv.x = acc[j][0] + b4.x;
        hv.y = acc[j][1] + b4.y;
        hv.z = acc[j][2] + b4.z;
        hv.w = acc[j][3] + b4.w;
        *reinterpret_cast<float4*>(&h[(r0 + rg * 8 + j) * 128 + cg * 4]) = hv;
        s1[0] += hv.x; s2[0] += hv.x * hv.x;
        s1[1] += hv.y; s2[1] += hv.y * hv.y;
        s1[2] += hv.z; s2[2] += hv.z * hv.z;
        s1[3] += hv.w; s2[3] += hv.w * hv.w;
    }
    #pragma unroll
    for (int cc = 0; cc < 4; ++cc) {
        st[(rg * 128 + cg * 4 + cc) * 2 + 0] = s1[cc];
        st[(rg * 128 + cg * 4 + cc) * 2 + 1] = s2[cc];
    }
    __syncthreads();
    if (t < 128) {
        float a = 0.0f, q = 0.0f;
        #pragma unroll
        for (int g = 0; g < 8; ++g) {
            a += st[(g * 128 + t) * 2 + 0];
            q += st[(g * 128 + t) * 2 + 1];
        }
        psum[blockIdx.x * 128 + t] = a;
        psumsq[blockIdx.x * 128 + t] = q;
    }
}

// ---------------------------------------------------------------------------
__global__ void bn_finalize_kernel(const float* __restrict__ psum, const float* __restrict__ psumsq,
                                   const float* __restrict__ gamma, const float* __restrict__ beta,
                                   float* __restrict__ scale, float* __restrict__ shift) {
    int c = threadIdx.x;
    float s = 0.0f, q = 0.0f;
    #pragma unroll 8
    for (int p = 0; p < 512; ++p) {
        s += psum[p * 128 + c];
        q += psumsq[p * 128 + c];
    }
    float mean = s * (1.0f / N_PTS);
    float var = q * (1.0f / N_PTS) - mean * mean;
    float sc = gamma[c] * rsqrtf(var + BN_EPS_C);
    scale[c] = sc;
    shift[c] = beta[c] - mean * sc;
}

// ---------------------------------------------------------------------------
// 4) kNN: one wave per query; per-lane top-16 lex (d, idx); shuffle merge.
__global__ __launch_bounds__(256) void knn_kernel(
    const float* __restrict__ posx, const float* __restrict__ posy, const float* __restrict__ posz,
    const int* __restrict__ ids, int* __restrict__ nn) {
    const int lane = threadIdx.x & 63;
    const int q = blockIdx.x * 4 + (threadIdx.x >> 6);
    const int qi = ids[q];
    const float qx = posx[qi], qy = posy[qi], qz = posz[qi];

    float dv[16]; int di[16];
    #pragma unroll
    for (int j = 0; j < 16; ++j) { dv[j] = FLT_MAX; di[j] = 0x7fffffff; }
    float wm = FLT_MAX; int wmi = 0x7fffffff; int wslot = 0;

    for (int s = 0; s < N_PTS / 64; ++s) {
        int i = s * 64 + lane;
        float dx = posx[i] - qx, dy = posy[i] - qy, dz = posz[i] - qz;
        float d = fmaf(dx, dx, fmaf(dy, dy, dz * dz));
        if (d < wm || (d == wm && i < wmi)) {
            #pragma unroll
            for (int j = 0; j < 16; ++j)
                if (j == wslot) { dv[j] = d; di[j] = i; }
            wm = -1.0f; wmi = -1;
            #pragma unroll
            for (int j = 0; j < 16; ++j) {
                bool g = (dv[j] > wm) || (dv[j] == wm && di[j] > wmi);
                if (g) { wm = dv[j]; wmi = di[j]; wslot = j; }
            }
        }
    }
    for (int rr = 0; rr < 16; ++rr) {
        float bv = FLT_MAX; int bidx = 0x7fffffff;
        #pragma unroll
        for (int j = 0; j < 16; ++j) {
            bool g = (dv[j] < bv) || (dv[j] == bv && di[j] < bidx);
            if (g) { bv = dv[j]; bidx = di[j]; }
        }
        #pragma unroll
        for (int off = 32; off; off >>= 1) {
            float ov = __shfl_xor(bv, off);
            int oi = __shfl_xor(bidx, off);
            if (ov < bv || (ov == bv && oi < bidx)) { bv = ov; bidx = oi; }
        }
        if (lane == 0) nn[q * 16 + rr] = bidx;
        #pragma unroll
        for (int j = 0; j < 16; ++j)
            if (di[j] == bidx) { dv[j] = FLT_MAX; di[j] = 0x7fffffff; }
    }
}

// ---------------------------------------------------------------------------
__global__ __launch_bounds__(256) void pool_kernel(
    const float* __restrict__ h, const int* __restrict__ nn,
    const float* __restrict__ scale, const float* __restrict__ shift,
    float* __restrict__ out) {
    const int t = threadIdx.x;
    const int c = t & 127;
    const int m = blockIdx.x * 2 + (t >> 7);
    const float sc = scale[c], sh = shift[c];
    float mx = -FLT_MAX;
    #pragma unroll
    for (int k = 0; k < 16; ++k) {
        int n = nn[m * 16 + k];
        float hv = h[n * 128 + c];
        mx = fmaxf(mx, fmaf(hv, sc, sh));
    }
    out[m * 128 + c] = fmaxf(mx, 0.0f);
}

// ---------------------------------------------------------------------------
extern "C" void kernel_launch(void* const* d_in, const int* in_sizes, int n_in,
                              void* d_out, int out_size, void* d_ws, size_t ws_size,
                              hipStream_t stream) {
    const float* x     = (const float*)d_in[0];
    const float* pos   = (const float*)d_in[1];
    const int*   batch = (const int*)d_in[2];
    const float* W     = (const float*)d_in[3];
    const float* b     = (const float*)d_in[4];
    const float* gamma = (const float*)d_in[5];
    const float* beta  = (const float*)d_in[6];
    (void)in_sizes; (void)n_in; (void)out_size; (void)ws_size;

    float* out       = (float*)d_out;
    float* sub_pos   = out + (size_t)M_CL * OUT_C;
    float* sub_batch = sub_pos + (size_t)M_CL * 3;

    char* w8 = (char*)d_ws;
    float* posx   = (float*)(w8 + 0);
    float* posy   = (float*)(w8 + 131072);
    float* posz   = (float*)(w8 + 262144);
    float* psx    = (float*)(w8 + 393216);
    float* psy    = (float*)(w8 + 524288);
    float* psz    = (float*)(w8 + 655360);
    int*   soidx  = (int*)  (w8 + 786432);
    int*   cellid = (int*)  (w8 + 917504);
    int*   hist   = (int*)  (w8 + 1048576);
    int*   startb = (int*)  (w8 + 1064960);
    int*   cur    = (int*)  (w8 + 1081344);
    int*   ids    = (int*)  (w8 + 1097728);
    int*   nn     = (int*)  (w8 + 1130496);
    int*   probed = (int*)  (w8 + 1654784);
    // dead-region reuse (stream-ordered):
    float* psum   = (float*)(w8 + 393216);   // over psx/psy (dead after fps)
    float* psumsq = (float*)(w8 + 655360);   // over psz/soidx (dead after fps)
    float* scale  = (float*)(w8 + 1048576);  // over hist (dead after scatter)
    float* shift  = (float*)(w8 + 1049088);
    float* h      = (float*)(w8 + 2097152);

    zero_kernel<<<32, 256, 0, stream>>>(hist, cur);
    prep_kernel<<<128, 256, 0, stream>>>(pos, posx, posy, posz, cellid, hist);
    scan_kernel<<<1, 1024, 0, stream>>>(hist, startb);
    scatter_kernel<<<128, 256, 0, stream>>>(posx, posy, posz, cellid, startb, cur,
                                            psx, psy, psz, soidx);
    fps_probe<<<1, 512, 0, stream>>>(probed);
    fps_kernel<<<1, 512, 0, stream>>>(psx, psy, psz, soidx,
                                      posx, posy, posz,
                                      ids, sub_pos);
    sub_batch_kernel<<<32, 256, 0, stream>>>(ids, batch, sub_batch);
    gemm_stats_kernel<<<512, 256, 0, stream>>>(x, W, b, h, psum, psumsq);
    bn_finalize_kernel<<<1, 128, 0, stream>>>(psum, psumsq, gamma, beta, scale, shift);
    knn_kernel<<<2048, 256, 0, stream>>>(posx, posy, posz, ids, nn);
    pool_kernel<<<4096, 256, 0, stream>>>(h, nn, scale, shift, out);
}

// Round 7
// 23100.926 us; speedup vs baseline: 3.1141x; 1.9119x over previous
//
#include <hip/hip_runtime.h>
#include <float.h>

// TransitionDown: FPS -> kNN(16) -> Linear(64,128)+BN(train stats)+ReLU -> neighborhood max
#define N_PTS 32768
#define M_CL  8192
#define IN_C  64
#define OUT_C 128
#define K_NN  16
constexpr float BN_EPS_C = 1e-5f;

// ---------------- ws layout (bytes) ----------------
// 0        posx [N] f32          (prep -> fps/knn)
// 131072   posy [N]
// 262144   posz [N]
// 393216   psx  [N] sorted       (scatter -> fps)   [psum after fps]
// 524288   psy  [N]
// 655360   psz  [N]              [psumsq after fps]
// 786432   soidx[N] int
// 917504   cellid [N] int        (prep -> scatter)
// 1048576  hist [4096] int       [scale/shift after scatter]
// 1064960  start [4096] int
// 1081344  cur  [4096] int
// 1097728  ids  [M] int          (fps -> knn/sub_batch)
// 1130496  nn   [M*16] int       (knn -> pool)      ends 1654784
// 2097152  h [N*128] f32 (16 MiB) -> end 18874368

// ---------------------------------------------------------------------------
__global__ void zero_kernel(int* __restrict__ hist, int* __restrict__ cur) {
    int i = blockIdx.x * 256 + threadIdx.x;
    if (i < 4096) { hist[i] = 0; cur[i] = 0; }
}

__device__ __forceinline__ unsigned sp4(unsigned x) {
    x = (x | (x << 4)) & 0xC3u;
    x = (x | (x << 2)) & 0x249u;
    return x;
}

// 0) SoA split + Morton cell id + histogram
__global__ void prep_kernel(const float* __restrict__ pos,
                            float* __restrict__ px, float* __restrict__ py, float* __restrict__ pz,
                            int* __restrict__ cellid, int* __restrict__ hist) {
    int i = blockIdx.x * 256 + threadIdx.x;
    if (i >= N_PTS) return;
    float x = pos[3 * i + 0], y = pos[3 * i + 1], z = pos[3 * i + 2];
    px[i] = x; py[i] = y; pz[i] = z;
    int cx = (int)floorf((x + 4.0f) * 2.0f); cx = min(15, max(0, cx));
    int cy = (int)floorf((y + 4.0f) * 2.0f); cy = min(15, max(0, cy));
    int cz = (int)floorf((z + 4.0f) * 2.0f); cz = min(15, max(0, cz));
    int c = (int)(sp4((unsigned)cx) | (sp4((unsigned)cy) << 1) | (sp4((unsigned)cz) << 2));
    cellid[i] = c;
    atomicAdd(&hist[c], 1);
}

// exclusive prefix sum over 4096 bins
__global__ __launch_bounds__(1024) void scan_kernel(const int* __restrict__ hist,
                                                    int* __restrict__ start) {
    __shared__ int wtotI[16];
    const int tid = threadIdx.x;
    const int lane = tid & 63, w = tid >> 6;
    int4 hv = *reinterpret_cast<const int4*>(&hist[tid * 4]);
    int a0 = hv.x, a1 = a0 + hv.y, a2 = a1 + hv.z, a3 = a2 + hv.w;
    int tsum = a3;
    int v = tsum;
    #pragma unroll
    for (int off = 1; off < 64; off <<= 1) {
        int o = __shfl_up(v, off);
        if (lane >= off) v += o;
    }
    if (lane == 63) wtotI[w] = v;
    __syncthreads();
    if (tid < 16) {
        int v2 = wtotI[tid];
        #pragma unroll
        for (int off = 1; off < 16; off <<= 1) {
            int o = __shfl_up(v2, off);
            if (tid >= off) v2 += o;
        }
        wtotI[tid] = v2;
    }
    __syncthreads();
    int base = (w > 0 ? wtotI[w - 1] : 0) + (v - tsum);
    int4 sv;
    sv.x = base; sv.y = base + a0; sv.z = base + a1; sv.w = base + a2;
    *reinterpret_cast<int4*>(&start[tid * 4]) = sv;
}

__global__ void scatter_kernel(const float* __restrict__ px, const float* __restrict__ py,
                               const float* __restrict__ pz, const int* __restrict__ cellid,
                               const int* __restrict__ start, int* __restrict__ cur,
                               float* __restrict__ psx, float* __restrict__ psy,
                               float* __restrict__ psz, int* __restrict__ soidx) {
    int i = blockIdx.x * 256 + threadIdx.x;
    if (i >= N_PTS) return;
    int c = cellid[i];
    int p = start[c] + atomicAdd(&cur[c], 1);
    psx[p] = px[i]; psy[p] = py[i]; psz[p] = pz[i];
    soidx[p] = i;
}

// ---------------------------------------------------------------------------
__device__ __forceinline__ unsigned long long shfl_xor_u64(unsigned long long v, int off) {
    unsigned lo = (unsigned)v, hi = (unsigned)(v >> 32);
    lo = __shfl_xor(lo, off);
    hi = __shfl_xor(hi, off);
    return ((unsigned long long)hi << 32) | (unsigned long long)lo;
}

// 1) FPS: shared region meta + work-queue load balancing.
//    512 thr / 8 waves; region = 64 sorted points (512 regions). Meta
//    (ckey,cen,rad,argmax coords) in LDS so ANY wave can update ANY region.
//    Per step: all 512 threads prune-test one region each -> ballot-compacted
//    queue -> waves process entries round-robin (i=w; i+=8) with 1-ahead
//    prefetch -> dirty groups re-reduce partials. 3 barriers/step.
//    Key u64 = (f32bits(min_d)<<32)|(0x7fffffff-origidx); u64 max ==
//    (min_d desc, idx asc) == np.argmax first-occurrence.
//    Distances bit-identical to jax f32 (unfused, (xx+yy)+zz).
__global__ __launch_bounds__(512) void fps_kernel(
    const float* __restrict__ psx, const float* __restrict__ psy, const float* __restrict__ psz,
    const int* __restrict__ soidx,
    const float* __restrict__ posx, const float* __restrict__ posy, const float* __restrict__ posz,
    int* __restrict__ ids, float* __restrict__ out_subpos) {
    #pragma clang fp contract(off)
    __shared__ __align__(16) float mdL[N_PTS];        // 128 KiB
    __shared__ unsigned long long ckeyL[512];         // 4 KiB
    __shared__ float cenxL[512], cenyL[512], cenzL[512], radL[512];  // 8 KiB
    __shared__ float ccxL[512], ccyL[512], cczL[512]; // 6 KiB
    __shared__ unsigned long long partK[2][8];
    __shared__ float partX[2][8], partY[2][8], partZ[2][8];
    __shared__ int queue[512];
    __shared__ int qcnt;
    __shared__ int dirty[8];

    const int tid = threadIdx.x;
    const int lane = tid & 63, w = tid >> 6;

    const float s0x = posx[0], s0y = posy[0], s0z = posz[0];

    // ---- init: wave w fills regions [w*64, w*64+64) cooperatively ----
    for (int k = 0; k < 64; ++k) {
        const int r = (w << 6) + k;
        const int gi = (r << 6) + lane;
        float X = psx[gi], Y = psy[gi], Z = psz[gi];
        int   o = soidx[gi];
        float mnx = X, mxx = X, mny = Y, mxy = Y, mnz = Z, mxz = Z;
        float dx = X - s0x;
        float dy = Y - s0y;
        float dz = Z - s0z;
        float xx = dx * dx, yy = dy * dy, zz = dz * dz;
        float d = (xx + yy) + zz;
        mdL[gi] = d;
        unsigned long long kp = ((unsigned long long)__float_as_uint(d) << 32)
                              | (unsigned long long)(0x7fffffffu - (unsigned)o);
        unsigned long long wp = kp;
        #pragma unroll
        for (int off = 32; off; off >>= 1) {
            unsigned long long ok = shfl_xor_u64(wp, off);
            if (ok > wp) wp = ok;
            mnx = fminf(mnx, __shfl_xor(mnx, off)); mxx = fmaxf(mxx, __shfl_xor(mxx, off));
            mny = fminf(mny, __shfl_xor(mny, off)); mxy = fmaxf(mxy, __shfl_xor(mxy, off));
            mnz = fminf(mnz, __shfl_xor(mnz, off)); mxz = fmaxf(mxz, __shfl_xor(mxz, off));
        }
        unsigned long long eqm = __ballot(kp == wp);
        int wl = (int)__ffsll(eqm) - 1;
        float mx_ = __shfl(X, wl), my_ = __shfl(Y, wl), mz_ = __shfl(Z, wl);
        if (lane == 0) {
            float cx = 0.5f * (mnx + mxx), cy = 0.5f * (mny + mxy), cz = 0.5f * (mnz + mxz);
            float hx = mxx - cx, hy = mxy - cy, hz = mxz - cz;
            cenxL[r] = cx; cenyL[r] = cy; cenzL[r] = cz;
            radL[r] = sqrtf((hx * hx + hy * hy) + hz * hz) * 1.0005f + 1e-6f;
            ckeyL[r] = wp; ccxL[r] = mx_; ccyL[r] = my_; cczL[r] = mz_;
        }
    }
    if (tid == 0) {
        ids[0] = 0;
        out_subpos[0] = s0x; out_subpos[1] = s0y; out_subpos[2] = s0z;
        qcnt = 0;
    }
    if (tid < 8) dirty[tid] = 0;
    __syncthreads();
    // initial per-wave partials over own 64 regions
    {
        unsigned long long wk = ckeyL[(w << 6) + lane];
        float wx = ccxL[(w << 6) + lane], wy = ccyL[(w << 6) + lane], wz = cczL[(w << 6) + lane];
        #pragma unroll
        for (int off = 32; off; off >>= 1) {
            unsigned long long ok = shfl_xor_u64(wk, off);
            float ox = __shfl_xor(wx, off), oy = __shfl_xor(wy, off), oz = __shfl_xor(wz, off);
            if (ok > wk) { wk = ok; wx = ox; wy = oy; wz = oz; }
        }
        if (lane == 0) { partK[1][w] = wk; partX[1][w] = wx; partY[1][w] = wy; partZ[1][w] = wz; }
    }
    __syncthreads();

    // ---- main loop ----
    for (int t = 1; t < M_CL; ++t) {
        const int tb = t & 1, nb = (t + 1) & 1;
        // A: redundant final reduce over 8 wave partials
        unsigned long long bk = partK[tb][0];
        float sx = partX[tb][0], sy = partY[tb][0], sz = partZ[tb][0];
        #pragma unroll
        for (int u = 1; u < 8; ++u) {
            unsigned long long ok = partK[tb][u];
            if (ok > bk) { bk = ok; sx = partX[tb][u]; sy = partY[tb][u]; sz = partZ[tb][u]; }
        }
        if (tid == 0) {
            ids[t] = (int)(0x7fffffffu - (unsigned)(bk & 0xffffffffu));
            out_subpos[3 * t + 0] = sx;
            out_subpos[3 * t + 1] = sy;
            out_subpos[3 * t + 2] = sz;
        }
        // B: each thread prune-tests region `tid`; ballot-compacted enqueue
        float ex = sx - cenxL[tid], ey = sy - cenyL[tid], ez = sz - cenzL[tid];
        float dc2 = (ex * ex + ey * ey) + ez * ez;
        float lb = sqrtf(dc2) * 0.9995f - radL[tid];
        float cmaxf = __uint_as_float((unsigned)(ckeyL[tid] >> 32));
        bool aff = !(lb > 0.0f && lb * lb * 0.999f >= cmaxf);
        unsigned long long mB = __ballot(aff);
        int cnt = __popcll(mB);
        int base = 0;
        if (lane == 0 && cnt) base = atomicAdd(&qcnt, cnt);
        base = __shfl(base, 0);
        if (aff) {
            int pos = base + (int)__popcll(mB & ((1ull << lane) - 1ull));
            queue[pos] = tid;
        }
        __syncthreads();  // bar1: queue ready

        // C: waves process queue round-robin, 1-ahead coord prefetch
        const int qn = qcnt;
        int i = w;
        if (i < qn) {
            int rA = queue[i];
            int giA = (rA << 6) + lane;
            float xA = psx[giA], yA = psy[giA], zA = psz[giA];
            int oA = soidx[giA];
            while (i < qn) {
                int i2 = i + 8;
                int rB = 0; float xB = 0, yB = 0, zB = 0; int oB = 0;
                if (i2 < qn) {
                    rB = queue[i2];
                    int giB = (rB << 6) + lane;
                    xB = psx[giB]; yB = psy[giB]; zB = psz[giB]; oB = soidx[giB];
                }
                const int gi = (rA << 6) + lane;
                float dx = xA - sx;
                float dy = yA - sy;
                float dz = zA - sz;
                float xx = dx * dx, yy = dy * dy, zz = dz * dz;
                float d = (xx + yy) + zz;
                float old = mdL[gi];
                float nm = fminf(old, d);
                bool chg = nm < old;
                if (chg) mdL[gi] = nm;
                if (__ballot(chg)) {
                    unsigned long long rk = ckeyL[rA];  // broadcast
                    float cmaxR = __uint_as_float((unsigned)(rk >> 32));
                    unsigned idxR = 0x7fffffffu - (unsigned)(rk & 0xffffffffu);
                    bool danger = chg && (((unsigned)oA == idxR) || (nm == cmaxR));
                    if (__ballot(danger)) {
                        unsigned long long kp = ((unsigned long long)__float_as_uint(nm) << 32)
                                              | (unsigned long long)(0x7fffffffu - (unsigned)oA);
                        unsigned long long wp = kp;
                        #pragma unroll
                        for (int off = 32; off; off >>= 1) {
                            unsigned long long ok = shfl_xor_u64(wp, off);
                            if (ok > wp) wp = ok;
                        }
                        unsigned long long eqm = __ballot(kp == wp);
                        int wl = (int)__ffsll(eqm) - 1;
                        float mx_ = __shfl(xA, wl), my_ = __shfl(yA, wl), mz_ = __shfl(zA, wl);
                        if (lane == 0) {
                            ckeyL[rA] = wp; ccxL[rA] = mx_; ccyL[rA] = my_; cczL[rA] = mz_;
                            dirty[rA >> 6] = 1;
                        }
                    }
                }
                i = i2; rA = rB; xA = xB; yA = yB; zA = zB; oA = oB;
            }
        }
        __syncthreads();  // bar2: all md/meta updates visible

        // D: dirty groups re-reduce their partial; clean groups copy forward
        if (tid == 0) qcnt = 0;
        if (dirty[w]) {
            unsigned long long wk = ckeyL[(w << 6) + lane];
            float wx = ccxL[(w << 6) + lane], wy = ccyL[(w << 6) + lane], wz = cczL[(w << 6) + lane];
            #pragma unroll
            for (int off = 32; off; off >>= 1) {
                unsigned long long ok = shfl_xor_u64(wk, off);
                float ox = __shfl_xor(wx, off), oy = __shfl_xor(wy, off), oz = __shfl_xor(wz, off);
                if (ok > wk) { wk = ok; wx = ox; wy = oy; wz = oz; }
            }
            if (lane == 0) {
                partK[nb][w] = wk; partX[nb][w] = wx; partY[nb][w] = wy; partZ[nb][w] = wz;
                dirty[w] = 0;
            }
        } else if (lane == 0) {
            partK[nb][w] = partK[tb][w];
            partX[nb][w] = partX[tb][w]; partY[nb][w] = partY[tb][w]; partZ[nb][w] = partZ[tb][w];
        }
        __syncthreads();  // bar3: partials ready for next A
    }
}

// ---------------------------------------------------------------------------
// sub_batch gather (off the fps critical path)
__global__ void sub_batch_kernel(const int* __restrict__ ids, const int* __restrict__ batch,
                                 float* __restrict__ sub_batch) {
    int i = blockIdx.x * 256 + threadIdx.x;
    if (i < M_CL) sub_batch[i] = (float)batch[ids[i]];
}

// ---------------------------------------------------------------------------
// 2) GEMM h = x@W + b (f32 vector ALU) + fused per-block column sum / sumsq.
__global__ __launch_bounds__(256) void gemm_stats_kernel(
    const float* __restrict__ x, const float* __restrict__ W, const float* __restrict__ bias,
    float* __restrict__ h, float* __restrict__ psum, float* __restrict__ psumsq) {
    __shared__ __align__(16) float Wl[64 * 128];
    __shared__ float xl[64 * 64];
    __shared__ float st[8 * 128 * 2];

    const int t = threadIdx.x;
    const int r0 = blockIdx.x * 64;
    #pragma unroll
    for (int u = 0; u < 32; ++u) Wl[u * 256 + t] = W[u * 256 + t];
    #pragma unroll
    for (int u = 0; u < 16; ++u) { int f = u * 256 + t; xl[f] = x[r0 * 64 + f]; }
    __syncthreads();

    const int cg = t & 31;
    const int rg = t >> 5;
    float acc[8][4];
    #pragma unroll
    for (int j = 0; j < 8; ++j)
        #pragma unroll
        for (int cc = 0; cc < 4; ++cc) acc[j][cc] = 0.0f;

    #pragma unroll 4
    for (int k = 0; k < 64; ++k) {
        float4 w4 = *reinterpret_cast<const float4*>(&Wl[k * 128 + cg * 4]);
        #pragma unroll
        for (int j = 0; j < 8; ++j) {
            float xv = xl[(rg * 8 + j) * 64 + k];
            acc[j][0] = fmaf(xv, w4.x, acc[j][0]);
            acc[j][1] = fmaf(xv, w4.y, acc[j][1]);
            acc[j][2] = fmaf(xv, w4.z, acc[j][2]);
            acc[j][3] = fmaf(xv, w4.w, acc[j][3]);
        }
    }
    float4 b4 = *reinterpret_cast<const float4*>(&bias[cg * 4]);
    float s1[4] = {0, 0, 0, 0}, s2[4] = {0, 0, 0, 0};
    #pragma unroll
    for (int j = 0; j < 8; ++j) {
        float4 hv;
        hv.x = acc[j][0] + b4.x;
        hv.y = acc[j][1] + b4.y;
        hv.z = acc[j][2] + b4.z;
        hv.w = acc[j][3] + b4.w;
        *reinterpret_cast<float4*>(&h[(r0 + rg * 8 + j) * 128 + cg * 4]) = hv;
        s1[0] += hv.x; s2[0] += hv.x * hv.x;
        s1[1] += hv.y; s2[1] += hv.y * hv.y;
        s1[2] += hv.z; s2[2] += hv.z * hv.z;
        s1[3] += hv.w; s2[3] += hv.w * hv.w;
    }
    #pragma unroll
    for (int cc = 0; cc < 4; ++cc) {
        st[(rg * 128 + cg * 4 + cc) * 2 + 0] = s1[cc];
        st[(rg * 128 + cg * 4 + cc) * 2 + 1] = s2[cc];
    }
    __syncthreads();
    if (t < 128) {
        float a = 0.0f, q = 0.0f;
        #pragma unroll
        for (int g = 0; g < 8; ++g) {
            a += st[(g * 128 + t) * 2 + 0];
            q += st[(g * 128 + t) * 2 + 1];
        }
        psum[blockIdx.x * 128 + t] = a;
        psumsq[blockIdx.x * 128 + t] = q;
    }
}

// ---------------------------------------------------------------------------
__global__ void bn_finalize_kernel(const float* __restrict__ psum, const float* __restrict__ psumsq,
                                   const float* __restrict__ gamma, const float* __restrict__ beta,
                                   float* __restrict__ scale, float* __restrict__ shift) {
    int c = threadIdx.x;
    float s = 0.0f, q = 0.0f;
    #pragma unroll 8
    for (int p = 0; p < 512; ++p) {
        s += psum[p * 128 + c];
        q += psumsq[p * 128 + c];
    }
    float mean = s * (1.0f / N_PTS);
    float var = q * (1.0f / N_PTS) - mean * mean;
    float sc = gamma[c] * rsqrtf(var + BN_EPS_C);
    scale[c] = sc;
    shift[c] = beta[c] - mean * sc;
}

// ---------------------------------------------------------------------------
// 4) kNN: one wave per query; per-lane top-16 lex (d, idx); shuffle merge.
__global__ __launch_bounds__(256) void knn_kernel(
    const float* __restrict__ posx, const float* __restrict__ posy, const float* __restrict__ posz,
    const int* __restrict__ ids, int* __restrict__ nn) {
    const int lane = threadIdx.x & 63;
    const int q = blockIdx.x * 4 + (threadIdx.x >> 6);
    const int qi = ids[q];
    const float qx = posx[qi], qy = posy[qi], qz = posz[qi];

    float dv[16]; int di[16];
    #pragma unroll
    for (int j = 0; j < 16; ++j) { dv[j] = FLT_MAX; di[j] = 0x7fffffff; }
    float wm = FLT_MAX; int wmi = 0x7fffffff; int wslot = 0;

    for (int s = 0; s < N_PTS / 64; ++s) {
        int i = s * 64 + lane;
        float dx = posx[i] - qx, dy = posy[i] - qy, dz = posz[i] - qz;
        float d = fmaf(dx, dx, fmaf(dy, dy, dz * dz));
        if (d < wm || (d == wm && i < wmi)) {
            #pragma unroll
            for (int j = 0; j < 16; ++j)
                if (j == wslot) { dv[j] = d; di[j] = i; }
            wm = -1.0f; wmi = -1;
            #pragma unroll
            for (int j = 0; j < 16; ++j) {
                bool g = (dv[j] > wm) || (dv[j] == wm && di[j] > wmi);
                if (g) { wm = dv[j]; wmi = di[j]; wslot = j; }
            }
        }
    }
    for (int rr = 0; rr < 16; ++rr) {
        float bv = FLT_MAX; int bidx = 0x7fffffff;
        #pragma unroll
        for (int j = 0; j < 16; ++j) {
            bool g = (dv[j] < bv) || (dv[j] == bv && di[j] < bidx);
            if (g) { bv = dv[j]; bidx = di[j]; }
        }
        #pragma unroll
        for (int off = 32; off; off >>= 1) {
            float ov = __shfl_xor(bv, off);
            int oi = __shfl_xor(bidx, off);
            if (ov < bv || (ov == bv && oi < bidx)) { bv = ov; bidx = oi; }
        }
        if (lane == 0) nn[q * 16 + rr] = bidx;
        #pragma unroll
        for (int j = 0; j < 16; ++j)
            if (di[j] == bidx) { dv[j] = FLT_MAX; di[j] = 0x7fffffff; }
    }
}

// ---------------------------------------------------------------------------
__global__ __launch_bounds__(256) void pool_kernel(
    const float* __restrict__ h, const int* __restrict__ nn,
    const float* __restrict__ scale, const float* __restrict__ shift,
    float* __restrict__ out) {
    const int t = threadIdx.x;
    const int c = t & 127;
    const int m = blockIdx.x * 2 + (t >> 7);
    const float sc = scale[c], sh = shift[c];
    float mx = -FLT_MAX;
    #pragma unroll
    for (int k = 0; k < 16; ++k) {
        int n = nn[m * 16 + k];
        float hv = h[n * 128 + c];
        mx = fmaxf(mx, fmaf(hv, sc, sh));
    }
    out[m * 128 + c] = fmaxf(mx, 0.0f);
}

// ---------------------------------------------------------------------------
extern "C" void kernel_launch(void* const* d_in, const int* in_sizes, int n_in,
                              void* d_out, int out_size, void* d_ws, size_t ws_size,
                              hipStream_t stream) {
    const float* x     = (const float*)d_in[0];
    const float* pos   = (const float*)d_in[1];
    const int*   batch = (const int*)d_in[2];
    const float* W     = (const float*)d_in[3];
    const float* b     = (const float*)d_in[4];
    const float* gamma = (const float*)d_in[5];
    const float* beta  = (const float*)d_in[6];
    (void)in_sizes; (void)n_in; (void)out_size; (void)ws_size;

    float* out       = (float*)d_out;
    float* sub_pos   = out + (size_t)M_CL * OUT_C;
    float* sub_batch = sub_pos + (size_t)M_CL * 3;

    char* w8 = (char*)d_ws;
    float* posx   = (float*)(w8 + 0);
    float* posy   = (float*)(w8 + 131072);
    float* posz   = (float*)(w8 + 262144);
    float* psx    = (float*)(w8 + 393216);
    float* psy    = (float*)(w8 + 524288);
    float* psz    = (float*)(w8 + 655360);
    int*   soidx  = (int*)  (w8 + 786432);
    int*   cellid = (int*)  (w8 + 917504);
    int*   hist   = (int*)  (w8 + 1048576);
    int*   startb = (int*)  (w8 + 1064960);
    int*   cur    = (int*)  (w8 + 1081344);
    int*   ids    = (int*)  (w8 + 1097728);
    int*   nn     = (int*)  (w8 + 1130496);
    // dead-region reuse (stream-ordered):
    float* psum   = (float*)(w8 + 393216);   // over psx/psy (dead after fps)
    float* psumsq = (float*)(w8 + 655360);   // over psz/soidx (dead after fps)
    float* scale  = (float*)(w8 + 1048576);  // over hist (dead after scatter)
    float* shift  = (float*)(w8 + 1049088);
    float* h      = (float*)(w8 + 2097152);

    zero_kernel<<<32, 256, 0, stream>>>(hist, cur);
    prep_kernel<<<128, 256, 0, stream>>>(pos, posx, posy, posz, cellid, hist);
    scan_kernel<<<1, 1024, 0, stream>>>(hist, startb);
    scatter_kernel<<<128, 256, 0, stream>>>(posx, posy, posz, cellid, startb, cur,
                                            psx, psy, psz, soidx);
    fps_kernel<<<1, 512, 0, stream>>>(psx, psy, psz, soidx,
                                      posx, posy, posz,
                                      ids, sub_pos);
    sub_batch_kernel<<<32, 256, 0, stream>>>(ids, batch, sub_batch);
    gemm_stats_kernel<<<512, 256, 0, stream>>>(x, W, b, h, psum, psumsq);
    bn_finalize_kernel<<<1, 128, 0, stream>>>(psum, psumsq, gamma, beta, scale, shift);
    knn_kernel<<<2048, 256, 0, stream>>>(posx, posy, posz, ids, nn);
    pool_kernel<<<4096, 256, 0, stream>>>(h, nn, scale, shift, out);
}